// Round 2
// baseline (97.602 us; speedup 1.0000x reference)
//
#include <hip/hip_runtime.h>
#include <math.h>

// LDDMM variational RHS, Gaussian kernel sigma=0.1, B=1, N=8192, D=3.
// out[0:N*3]     = dmom_i = (1/sig^2) * (x_i * sum_j W_ij - sum_j W_ij x_j)
// out[N*3:2*N*3] = dcp_i  = sum_j K_ij p_j
// K_ij = exp(-|x_i-x_j|^2/(2 sig^2)), W_ij = K_ij*(p_i.p_j), p=clamp(mom,-1,1)
//
// R2: two-phase, atomic-free. Phase 1: 32 i-blocks x 64 j-chunks = 2048
// blocks (8192 waves -> 100% of wave slots; R1 had 28% occupancy) write
// per-chunk partials (dcp, wsum, wx as 2xfloat4) to d_ws. Phase 2: reduce
// over the 64 chunks + final combine. d2 expanded as |xi|^2+|xj|^2-2 dot
// with the exp2 coefficient pre-folded (cj lives in LDS float4.w): 16 VALU
// ops/pair vs 19 in R1. Falls back to R1's atomic path if ws too small.

#define NPTS 8192
#define N3   (NPTS * 3)
#define BI   256
#define JC   64
#define JLEN (NPTS / JC)   // 128
#define IB   (NPTS / BI)   // 32

// exp(-d2/(2*0.1^2)) = exp2(d2 * (-50*log2(e)))
#define COEF   (-72.134752044448170f)
#define M2COEF (144.269504088896340f)   // -2*COEF

#define WS_NEEDED ((size_t)JC * NPTS * 8 * sizeof(float))  // 16.78 MB

__device__ __forceinline__ float fast_exp2(float x) {
#if __has_builtin(__builtin_amdgcn_exp2f)
    return __builtin_amdgcn_exp2f(x);
#else
    return exp2f(x);
#endif
}

__device__ __forceinline__ float clamp1(float v) {
    return fminf(fmaxf(v, -1.0f), 1.0f);
}

// ws layout: ws[((c*NPTS)+i)*8 + k], k=0..3: dcp0,dcp1,dcp2,wsum; 4..7: wx0,wx1,wx2,0
__global__ __launch_bounds__(BI) void lddmm_partial(const float* __restrict__ mom,
                                                    const float* __restrict__ cp,
                                                    float* __restrict__ ws) {
    const int ib = (int)blockIdx.x / JC;
    const int jc = (int)blockIdx.x % JC;
    const int t  = (int)threadIdx.x;
    const int i  = ib * BI + t;

    const float xi0 = cp[i * 3 + 0];
    const float xi1 = cp[i * 3 + 1];
    const float xi2 = cp[i * 3 + 2];
    const float pi0 = clamp1(mom[i * 3 + 0]);
    const float pi1 = clamp1(mom[i * 3 + 1]);
    const float pi2 = clamp1(mom[i * 3 + 2]);
    const float ci  = COEF * (xi0 * xi0 + xi1 * xi1 + xi2 * xi2);

    __shared__ float4 shx[JLEN];  // xj0,xj1,xj2, COEF*|xj|^2
    __shared__ float4 shp[JLEN];  // pj0,pj1,pj2, 0
    if (t < JLEN) {
        const int j = jc * JLEN + t;
        const float x0 = cp[j * 3 + 0], x1 = cp[j * 3 + 1], x2 = cp[j * 3 + 2];
        shx[t] = make_float4(x0, x1, x2, COEF * (x0 * x0 + x1 * x1 + x2 * x2));
        shp[t] = make_float4(clamp1(mom[j * 3 + 0]), clamp1(mom[j * 3 + 1]),
                             clamp1(mom[j * 3 + 2]), 0.0f);
    }
    __syncthreads();

    float dcp0 = 0.f, dcp1 = 0.f, dcp2 = 0.f;
    float wsum = 0.f;
    float wx0 = 0.f, wx1 = 0.f, wx2 = 0.f;

#pragma unroll 8
    for (int jj = 0; jj < JLEN; ++jj) {
        const float4 xj = shx[jj];   // wave-uniform -> LDS broadcast
        const float4 pj = shp[jj];
        float dot = xi0 * xj.x;
        dot = fmaf(xi1, xj.y, dot);
        dot = fmaf(xi2, xj.z, dot);
        const float arg = fmaf(dot, M2COEF, ci + xj.w);  // COEF*d2
        const float K   = fast_exp2(arg);
        float pd = pi0 * pj.x;
        pd = fmaf(pi1, pj.y, pd);
        pd = fmaf(pi2, pj.z, pd);
        const float W = K * pd;
        dcp0 = fmaf(K, pj.x, dcp0);
        dcp1 = fmaf(K, pj.y, dcp1);
        dcp2 = fmaf(K, pj.z, dcp2);
        wsum += W;
        wx0 = fmaf(W, xj.x, wx0);
        wx1 = fmaf(W, xj.y, wx1);
        wx2 = fmaf(W, xj.z, wx2);
    }

    float4* o = (float4*)(ws + ((size_t)(jc * NPTS) + i) * 8);
    o[0] = make_float4(dcp0, dcp1, dcp2, wsum);
    o[1] = make_float4(wx0, wx1, wx2, 0.0f);
}

// 16384 threads: 2 per i. half0 sums (dcp,wsum) float4s, half1 sums (wx,0).
__global__ __launch_bounds__(256) void lddmm_reduce(const float* __restrict__ ws,
                                                    const float* __restrict__ cp,
                                                    float* __restrict__ out) {
    const int tid  = (int)blockIdx.x * 256 + (int)threadIdx.x;
    const int i    = tid >> 1;
    const int half = tid & 1;

    float4 acc = make_float4(0.f, 0.f, 0.f, 0.f);
#pragma unroll 4
    for (int c = 0; c < JC; ++c) {
        const float4 v = ((const float4*)(ws + ((size_t)(c * NPTS) + i) * 8))[half];
        acc.x += v.x; acc.y += v.y; acc.z += v.z; acc.w += v.w;
    }
    // lanes (2k,2k+1) pair up; xor-1 hands half0's acc.w (wsum) to half1
    const float wsum = __shfl_xor(acc.w, 1);
    if (half == 0) {
        out[N3 + i * 3 + 0] = acc.x;
        out[N3 + i * 3 + 1] = acc.y;
        out[N3 + i * 3 + 2] = acc.z;
    } else {
        const float xi0 = cp[i * 3 + 0];
        const float xi1 = cp[i * 3 + 1];
        const float xi2 = cp[i * 3 + 2];
        out[i * 3 + 0] = 100.0f * (xi0 * wsum - acc.x);
        out[i * 3 + 1] = 100.0f * (xi1 * wsum - acc.y);
        out[i * 3 + 2] = 100.0f * (xi2 * wsum - acc.z);
    }
}

// ---- R1 fallback (atomics into d_out) if ws_size < WS_NEEDED ----
#define FJC   32
#define FJLEN (NPTS / FJC)
__global__ __launch_bounds__(BI) void lddmm_pairs_atomic(const float* __restrict__ mom,
                                                         const float* __restrict__ cp,
                                                         float* __restrict__ out) {
    const int ib = (int)blockIdx.x / FJC;
    const int jc = (int)blockIdx.x % FJC;
    const int t  = (int)threadIdx.x;
    const int i  = ib * BI + t;

    const float xi0 = cp[i * 3 + 0], xi1 = cp[i * 3 + 1], xi2 = cp[i * 3 + 2];
    const float pi0 = clamp1(mom[i * 3 + 0]), pi1 = clamp1(mom[i * 3 + 1]),
                pi2 = clamp1(mom[i * 3 + 2]);

    __shared__ float4 shx[FJLEN];
    __shared__ float4 shp[FJLEN];
    {
        const int j = jc * FJLEN + t;
        shx[t] = make_float4(cp[j * 3 + 0], cp[j * 3 + 1], cp[j * 3 + 2], 0.0f);
        shp[t] = make_float4(clamp1(mom[j * 3 + 0]), clamp1(mom[j * 3 + 1]),
                             clamp1(mom[j * 3 + 2]), 0.0f);
    }
    __syncthreads();

    float dcp0 = 0.f, dcp1 = 0.f, dcp2 = 0.f, wsum = 0.f, wx0 = 0.f, wx1 = 0.f, wx2 = 0.f;
#pragma unroll 4
    for (int jj = 0; jj < FJLEN; ++jj) {
        const float4 xj = shx[jj];
        const float4 pj = shp[jj];
        const float dx0 = xi0 - xj.x, dx1 = xi1 - xj.y, dx2 = xi2 - xj.z;
        const float d2  = dx0 * dx0 + dx1 * dx1 + dx2 * dx2;
        const float K   = fast_exp2(d2 * COEF);
        const float pd  = pi0 * pj.x + pi1 * pj.y + pi2 * pj.z;
        const float W   = K * pd;
        dcp0 += K * pj.x; dcp1 += K * pj.y; dcp2 += K * pj.z;
        wsum += W;
        wx0 += W * xj.x; wx1 += W * xj.y; wx2 += W * xj.z;
    }
    atomicAdd(&out[i * 3 + 0], 100.0f * (xi0 * wsum - wx0));
    atomicAdd(&out[i * 3 + 1], 100.0f * (xi1 * wsum - wx1));
    atomicAdd(&out[i * 3 + 2], 100.0f * (xi2 * wsum - wx2));
    atomicAdd(&out[N3 + i * 3 + 0], dcp0);
    atomicAdd(&out[N3 + i * 3 + 1], dcp1);
    atomicAdd(&out[N3 + i * 3 + 2], dcp2);
}

extern "C" void kernel_launch(void* const* d_in, const int* in_sizes, int n_in,
                              void* d_out, int out_size, void* d_ws, size_t ws_size,
                              hipStream_t stream) {
    const float* mom = (const float*)d_in[0];
    const float* cp  = (const float*)d_in[1];
    float* out = (float*)d_out;

    if (ws_size >= WS_NEEDED) {
        float* ws = (float*)d_ws;
        hipLaunchKernelGGL(lddmm_partial, dim3(IB * JC), dim3(BI), 0, stream, mom, cp, ws);
        hipLaunchKernelGGL(lddmm_reduce, dim3(NPTS * 2 / 256), dim3(256), 0, stream, ws, cp, out);
    } else {
        hipMemsetAsync(out, 0, (size_t)out_size * sizeof(float), stream);
        hipLaunchKernelGGL(lddmm_pairs_atomic, dim3(IB * FJC), dim3(BI), 0, stream, mom, cp, out);
    }
}

// Round 3
// 95.290 us; speedup vs baseline: 1.0243x; 1.0243x over previous
//
#include <hip/hip_runtime.h>
#include <math.h>

// LDDMM variational RHS, Gaussian kernel sigma=0.1, B=1, N=8192, D=3.
// out[0:N*3]     = dmom_i = (1/sig^2) * (x_i * sum_j W_ij - sum_j W_ij x_j)
// out[N*3:2*N*3] = dcp_i  = sum_j K_ij p_j
// K_ij = exp(-|x_i-x_j|^2/(2 sig^2)), W_ij = K_ij*(p_i.p_j), p=clamp(mom,-1,1)
//
// R3: R2's partial kernel was LDS-pipe-bound: 2x ds_read_b128 (~12cy each on
// the per-CU LDS return path) per 64 pairs = 98k cy/CU = 41 us, matching the
// measured 42.7 us. Fix: Mi=2 i-points per thread -> one LDS read pair feeds
// 128 pairs; LDS demand (24cy) now < VALU demand (80cy) per wave-iter ->
// VALU-bound, floor ~17 us. Grid 16 i-blocks x 64 j-chunks = 1024 blocks,
// __launch_bounds__(256,4) to keep VGPR<=128 (4 waves/SIMD).
// Phase 2: 4 threads/i (128 blocks), two-level shuffle combine.

#define NPTS 8192
#define N3   (NPTS * 3)
#define BI   256
#define MI   2                       // i-points per thread
#define IBLK (NPTS / (BI * MI))      // 16 i-blocks
#define JC   64
#define JLEN (NPTS / JC)             // 128

// exp(-d2/(2*0.1^2)) = exp2(d2 * (-50*log2(e)))
#define COEF   (-72.134752044448170f)
#define M2COEF (144.269504088896340f)   // -2*COEF

#define WS_NEEDED ((size_t)JC * NPTS * 8 * sizeof(float))  // 16.78 MB

__device__ __forceinline__ float fast_exp2(float x) {
#if __has_builtin(__builtin_amdgcn_exp2f)
    return __builtin_amdgcn_exp2f(x);
#else
    return exp2f(x);
#endif
}

__device__ __forceinline__ float clamp1(float v) {
    return fminf(fmaxf(v, -1.0f), 1.0f);
}

// ws layout: ws[((c*NPTS)+i)*8 + k], k=0..3: dcp0,dcp1,dcp2,wsum; 4..7: wx0,wx1,wx2,0
__global__ __launch_bounds__(BI, 4) void lddmm_partial(const float* __restrict__ mom,
                                                       const float* __restrict__ cp,
                                                       float* __restrict__ ws) {
    const int ib = (int)blockIdx.x / JC;
    const int jc = (int)blockIdx.x % JC;
    const int t  = (int)threadIdx.x;
    const int i0 = ib * (BI * MI) + t;
    const int i1 = i0 + BI;

    const float xa0 = cp[i0 * 3 + 0], xa1 = cp[i0 * 3 + 1], xa2 = cp[i0 * 3 + 2];
    const float xb0 = cp[i1 * 3 + 0], xb1 = cp[i1 * 3 + 1], xb2 = cp[i1 * 3 + 2];
    const float pa0 = clamp1(mom[i0 * 3 + 0]), pa1 = clamp1(mom[i0 * 3 + 1]),
                pa2 = clamp1(mom[i0 * 3 + 2]);
    const float pb0 = clamp1(mom[i1 * 3 + 0]), pb1 = clamp1(mom[i1 * 3 + 1]),
                pb2 = clamp1(mom[i1 * 3 + 2]);
    const float ca = COEF * (xa0 * xa0 + xa1 * xa1 + xa2 * xa2);
    const float cb = COEF * (xb0 * xb0 + xb1 * xb1 + xb2 * xb2);

    __shared__ float4 shx[JLEN];  // xj0,xj1,xj2, COEF*|xj|^2
    __shared__ float4 shp[JLEN];  // pj0,pj1,pj2, 0
    if (t < JLEN) {
        const int j = jc * JLEN + t;
        const float x0 = cp[j * 3 + 0], x1 = cp[j * 3 + 1], x2 = cp[j * 3 + 2];
        shx[t] = make_float4(x0, x1, x2, COEF * (x0 * x0 + x1 * x1 + x2 * x2));
        shp[t] = make_float4(clamp1(mom[j * 3 + 0]), clamp1(mom[j * 3 + 1]),
                             clamp1(mom[j * 3 + 2]), 0.0f);
    }
    __syncthreads();

    float a_dcp0 = 0.f, a_dcp1 = 0.f, a_dcp2 = 0.f, a_ws = 0.f;
    float a_wx0 = 0.f, a_wx1 = 0.f, a_wx2 = 0.f;
    float b_dcp0 = 0.f, b_dcp1 = 0.f, b_dcp2 = 0.f, b_ws = 0.f;
    float b_wx0 = 0.f, b_wx1 = 0.f, b_wx2 = 0.f;

#pragma unroll 4
    for (int jj = 0; jj < JLEN; ++jj) {
        const float4 xj = shx[jj];   // wave-uniform -> LDS broadcast
        const float4 pj = shp[jj];

        // i0
        float dota = xa0 * xj.x;
        dota = fmaf(xa1, xj.y, dota);
        dota = fmaf(xa2, xj.z, dota);
        const float Ka = fast_exp2(fmaf(dota, M2COEF, ca + xj.w));
        float pda = pa0 * pj.x;
        pda = fmaf(pa1, pj.y, pda);
        pda = fmaf(pa2, pj.z, pda);
        const float Wa = Ka * pda;
        a_dcp0 = fmaf(Ka, pj.x, a_dcp0);
        a_dcp1 = fmaf(Ka, pj.y, a_dcp1);
        a_dcp2 = fmaf(Ka, pj.z, a_dcp2);
        a_ws += Wa;
        a_wx0 = fmaf(Wa, xj.x, a_wx0);
        a_wx1 = fmaf(Wa, xj.y, a_wx1);
        a_wx2 = fmaf(Wa, xj.z, a_wx2);

        // i1
        float dotb = xb0 * xj.x;
        dotb = fmaf(xb1, xj.y, dotb);
        dotb = fmaf(xb2, xj.z, dotb);
        const float Kb = fast_exp2(fmaf(dotb, M2COEF, cb + xj.w));
        float pdb = pb0 * pj.x;
        pdb = fmaf(pb1, pj.y, pdb);
        pdb = fmaf(pb2, pj.z, pdb);
        const float Wb = Kb * pdb;
        b_dcp0 = fmaf(Kb, pj.x, b_dcp0);
        b_dcp1 = fmaf(Kb, pj.y, b_dcp1);
        b_dcp2 = fmaf(Kb, pj.z, b_dcp2);
        b_ws += Wb;
        b_wx0 = fmaf(Wb, xj.x, b_wx0);
        b_wx1 = fmaf(Wb, xj.y, b_wx1);
        b_wx2 = fmaf(Wb, xj.z, b_wx2);
    }

    float4* oa = (float4*)(ws + ((size_t)(jc * NPTS) + i0) * 8);
    oa[0] = make_float4(a_dcp0, a_dcp1, a_dcp2, a_ws);
    oa[1] = make_float4(a_wx0, a_wx1, a_wx2, 0.0f);
    float4* ob = (float4*)(ws + ((size_t)(jc * NPTS) + i1) * 8);
    ob[0] = make_float4(b_dcp0, b_dcp1, b_dcp2, b_ws);
    ob[1] = make_float4(b_wx0, b_wx1, b_wx2, 0.0f);
}

// 4 threads per i: sub = (cpart, half). Each sums JC/2 chunks of one float4,
// xor-2 combines chunk halves, xor-1 hands wsum from half0 to half1.
__global__ __launch_bounds__(256) void lddmm_reduce(const float* __restrict__ ws,
                                                    const float* __restrict__ cp,
                                                    float* __restrict__ out) {
    const int tid   = (int)blockIdx.x * 256 + (int)threadIdx.x;
    const int i     = tid >> 2;
    const int sub   = tid & 3;
    const int half  = sub & 1;
    const int cpart = sub >> 1;

    float4 acc = make_float4(0.f, 0.f, 0.f, 0.f);
    const int c0 = cpart * (JC / 2);
#pragma unroll 4
    for (int c = c0; c < c0 + JC / 2; ++c) {
        const float4 v = ((const float4*)(ws + ((size_t)(c * NPTS) + i) * 8))[half];
        acc.x += v.x; acc.y += v.y; acc.z += v.z; acc.w += v.w;
    }
    // combine the two chunk-halves (lanes differing in bit 1)
    acc.x += __shfl_xor(acc.x, 2);
    acc.y += __shfl_xor(acc.y, 2);
    acc.z += __shfl_xor(acc.z, 2);
    acc.w += __shfl_xor(acc.w, 2);
    // hand full wsum (half0's acc.w) to half1
    const float wsum = __shfl_xor(acc.w, 1);
    if (sub == 0) {
        out[N3 + i * 3 + 0] = acc.x;
        out[N3 + i * 3 + 1] = acc.y;
        out[N3 + i * 3 + 2] = acc.z;
    } else if (sub == 1) {
        const float xi0 = cp[i * 3 + 0];
        const float xi1 = cp[i * 3 + 1];
        const float xi2 = cp[i * 3 + 2];
        out[i * 3 + 0] = 100.0f * (xi0 * wsum - acc.x);
        out[i * 3 + 1] = 100.0f * (xi1 * wsum - acc.y);
        out[i * 3 + 2] = 100.0f * (xi2 * wsum - acc.z);
    }
}

// ---- fallback (atomics into d_out) if ws_size < WS_NEEDED ----
#define FJC   32
#define FJLEN (NPTS / FJC)
__global__ __launch_bounds__(BI) void lddmm_pairs_atomic(const float* __restrict__ mom,
                                                         const float* __restrict__ cp,
                                                         float* __restrict__ out) {
    const int ib = (int)blockIdx.x / FJC;
    const int jc = (int)blockIdx.x % FJC;
    const int t  = (int)threadIdx.x;
    const int i  = ib * BI + t;

    const float xi0 = cp[i * 3 + 0], xi1 = cp[i * 3 + 1], xi2 = cp[i * 3 + 2];
    const float pi0 = clamp1(mom[i * 3 + 0]), pi1 = clamp1(mom[i * 3 + 1]),
                pi2 = clamp1(mom[i * 3 + 2]);

    __shared__ float4 shx[FJLEN];
    __shared__ float4 shp[FJLEN];
    {
        const int j = jc * FJLEN + t;
        shx[t] = make_float4(cp[j * 3 + 0], cp[j * 3 + 1], cp[j * 3 + 2], 0.0f);
        shp[t] = make_float4(clamp1(mom[j * 3 + 0]), clamp1(mom[j * 3 + 1]),
                             clamp1(mom[j * 3 + 2]), 0.0f);
    }
    __syncthreads();

    float dcp0 = 0.f, dcp1 = 0.f, dcp2 = 0.f, wsum = 0.f, wx0 = 0.f, wx1 = 0.f, wx2 = 0.f;
#pragma unroll 4
    for (int jj = 0; jj < FJLEN; ++jj) {
        const float4 xj = shx[jj];
        const float4 pj = shp[jj];
        const float dx0 = xi0 - xj.x, dx1 = xi1 - xj.y, dx2 = xi2 - xj.z;
        const float d2  = dx0 * dx0 + dx1 * dx1 + dx2 * dx2;
        const float K   = fast_exp2(d2 * COEF);
        const float pd  = pi0 * pj.x + pi1 * pj.y + pi2 * pj.z;
        const float W   = K * pd;
        dcp0 += K * pj.x; dcp1 += K * pj.y; dcp2 += K * pj.z;
        wsum += W;
        wx0 += W * xj.x; wx1 += W * xj.y; wx2 += W * xj.z;
    }
    atomicAdd(&out[i * 3 + 0], 100.0f * (xi0 * wsum - wx0));
    atomicAdd(&out[i * 3 + 1], 100.0f * (xi1 * wsum - wx1));
    atomicAdd(&out[i * 3 + 2], 100.0f * (xi2 * wsum - wx2));
    atomicAdd(&out[N3 + i * 3 + 0], dcp0);
    atomicAdd(&out[N3 + i * 3 + 1], dcp1);
    atomicAdd(&out[N3 + i * 3 + 2], dcp2);
}

extern "C" void kernel_launch(void* const* d_in, const int* in_sizes, int n_in,
                              void* d_out, int out_size, void* d_ws, size_t ws_size,
                              hipStream_t stream) {
    const float* mom = (const float*)d_in[0];
    const float* cp  = (const float*)d_in[1];
    float* out = (float*)d_out;

    if (ws_size >= WS_NEEDED) {
        float* ws = (float*)d_ws;
        hipLaunchKernelGGL(lddmm_partial, dim3(IBLK * JC), dim3(BI), 0, stream, mom, cp, ws);
        hipLaunchKernelGGL(lddmm_reduce, dim3(NPTS * 4 / 256), dim3(256), 0, stream, ws, cp, out);
    } else {
        hipMemsetAsync(out, 0, (size_t)out_size * sizeof(float), stream);
        hipLaunchKernelGGL(lddmm_pairs_atomic, dim3((NPTS / BI) * FJC), dim3(BI), 0, stream, mom, cp, out);
    }
}